// Round 1
// baseline (1120.745 us; speedup 1.0000x reference)
//
#include <hip/hip_runtime.h>
#include <hip/hip_bf16.h>

typedef __attribute__((ext_vector_type(8))) short bf16x8;
typedef __attribute__((ext_vector_type(4))) float f32x4;
typedef unsigned int u32;
typedef const __attribute__((address_space(1))) u32 glb_u32;
typedef __attribute__((address_space(3))) u32 lds_u32;

#define NB 16
#define CI 512
#define CO 512
#define RESO 64
#define PC 66              // conv output spatial (64 + 2*2 - 3 + 1)
#define PADD 68            // padded input spatial
#define NCOLS (NB*PC*PC)   // 69696
#define NKT 144            // 4608 / 32

// workspace layout (bytes)
#define WS_STYLES 0ul              // 8192 f32
#define WS_SNORM  32768ul          // 1 f32
#define WS_D      33024ul          // 8192 f32
#define WS_W2     65792ul          // 512*512 f32
#define WS_AT     1114368ul        // 144*512*32 bf16 = 4718592
#define WS_XS     5832960ul        // 16*68*68*512 bf16 = 75759616
#define WS_CONV   81592576ul       // 16*512*66*66 bf16 = 71368704
// total = 152961280 bytes

// ---------------- styles = w @ aw^T / sqrt(512) + bias ----------------
__global__ void k_styles(const float* __restrict__ w, const float* __restrict__ aw,
                         const float* __restrict__ ab, float* __restrict__ styles) {
  int idx = blockIdx.x * 256 + threadIdx.x;   // 8192 = 16*512
  int n = idx >> 9, i = idx & 511;
  const float* wr = w + n * 512;
  const float* ar = aw + i * 512;
  float s = 0.f;
  for (int j = 0; j < 512; ++j) s += wr[j] * ar[j];
  styles[idx] = s * 0.04419417382415922f + ab[i];
}

// ---------------- snorm = rsqrt(mean(styles^2)) ----------------
__global__ void k_snorm(const float* __restrict__ styles, float* __restrict__ snorm) {
  __shared__ float red[256];
  float s = 0.f;
  for (int e = threadIdx.x; e < 8192; e += 256) { float v = styles[e]; s += v * v; }
  red[threadIdx.x] = s;
  __syncthreads();
  for (int st = 128; st > 0; st >>= 1) {
    if (threadIdx.x < st) red[threadIdx.x] += red[threadIdx.x + st];
    __syncthreads();
  }
  if (threadIdx.x == 0) snorm[0] = rsqrtf(red[0] / 8192.f);
}

// ---------------- weight prep: normalize per-o, write tiled bf16 A + W2 ----------------
// At layout: [kt=rs*16+ic][o][kk] ; K index = rs*512 + i, kt = K>>5, kk = K&31
__global__ void k_wprep(const float* __restrict__ cw, __hip_bfloat16* __restrict__ At,
                        float* __restrict__ W2) {
  int o = blockIdx.x;
  const float* base = cw + o * 4608;
  __shared__ float red[256];
  __shared__ float wnorm_s;
  float s = 0.f;
  for (int e = threadIdx.x; e < 4608; e += 256) { float v = base[e]; s += v * v; }
  red[threadIdx.x] = s;
  __syncthreads();
  for (int st = 128; st > 0; st >>= 1) {
    if (threadIdx.x < st) red[threadIdx.x] += red[threadIdx.x + st];
    __syncthreads();
  }
  if (threadIdx.x == 0) wnorm_s = rsqrtf(red[0] / 4608.f);
  __syncthreads();
  float wn = wnorm_s;
  for (int i = threadIdx.x; i < 512; i += 256) {
    const float* e9 = cw + (o * 512 + i) * 9;
    float w2 = 0.f;
    int ic = i >> 5, ik = i & 31;
#pragma unroll
    for (int rs = 0; rs < 9; ++rs) {
      float wv = e9[rs] * wn;
      w2 += wv * wv;
      At[((rs * 16 + ic) * 512 + o) * 32 + ik] = __float2bfloat16(wv);
    }
    W2[o * 512 + i] = w2;
  }
}

// ---------------- d[n,o] = rsqrt(snorm^2 * sum_i W2[o,i]*styles[n,i]^2 + 1e-8) ----------------
__global__ void k_dcalc(const float* __restrict__ W2, const float* __restrict__ styles,
                        const float* __restrict__ snorm, float* __restrict__ d) {
  int idx = blockIdx.x * 256 + threadIdx.x;   // n*512 + o
  int n = idx >> 9, o = idx & 511;
  const float* w2r = W2 + o * 512;
  const float* sr = styles + n * 512;
  float sum = 0.f;
  for (int i = 0; i < 512; ++i) { float sv = sr[i]; sum += w2r[i] * sv * sv; }
  float sn = snorm[0];
  d[idx] = rsqrtf(sn * sn * sum + 1e-8f);
}

// ---------------- zero xs_pad ----------------
__global__ void k_zero(uint4* __restrict__ p, long n16) {
  long i = (long)blockIdx.x * blockDim.x + threadIdx.x;
  long stride = (long)gridDim.x * blockDim.x;
  uint4 z = {0u, 0u, 0u, 0u};
  for (; i < n16; i += stride) p[i] = z;
}

// ---------------- scale by s[n,i], transpose NCHW -> N,H+4,W+4,C (bf16) ----------------
__global__ void k_scale_tr(const float* __restrict__ x, const float* __restrict__ styles,
                           const float* __restrict__ snorm, __hip_bfloat16* __restrict__ xs) {
  const int i0 = blockIdx.x * 64;
  const int p = blockIdx.y;
  const int n = blockIdx.z;
  __shared__ float tile[64][65];
  const float sn = snorm[0];
  const int lo = threadIdx.x & 63;
  const int hi = threadIdx.x >> 6;
#pragma unroll 4
  for (int rep = 0; rep < 16; ++rep) {
    int ii = hi + rep * 4;
    float sc = styles[n * 512 + i0 + ii] * sn;
    tile[ii][lo] = x[((n * 512 + i0 + ii) * 64 + p) * 64 + lo] * sc;
  }
  __syncthreads();
  const int obase = (n * 4624 + (p + 2) * 68 + 2) * 512 + i0;
#pragma unroll 4
  for (int rep = 0; rep < 16; ++rep) {
    int q = hi + rep * 4;
    xs[obase + q * 512 + lo] = __float2bfloat16(tile[lo][q]);
  }
}

// ---------------- implicit GEMM conv: C[o, (n,p,q)] = sum_K At[o,K] * B[K,(n,p,q)] ----------------
__device__ __forceinline__ int colbase_of(int c) {
  c = c < (NCOLS - 1) ? c : (NCOLS - 1);
  int n = (int)((unsigned)c / 4356u);
  int rem = c - n * 4356;
  int p = (int)((unsigned)rem / 66u);
  int q = rem - p * 66;
  return (n * 4624 + p * 68 + q) * 512;
}

#define BOFF(kt) (((((kt) >> 4) / 3) * 68 + (((kt) >> 4) % 3)) * 512 + ((kt) & 15) * 32)

__global__ __launch_bounds__(256) void k_gemm(
    const __hip_bfloat16* __restrict__ At, const __hip_bfloat16* __restrict__ xs,
    const float* __restrict__ dnorm, const float* __restrict__ cbias,
    __hip_bfloat16* __restrict__ cvt) {
  __shared__ __align__(16) __hip_bfloat16 Al[128 * 32];
  __shared__ __align__(16) __hip_bfloat16 Bl[128 * 32];
  const int tid = threadIdx.x;
  const int o0 = blockIdx.x * 128;   // 4 o-tiles
  const int c0 = blockIdx.y * 128;   // 545 col-tiles

  const int clA = tid >> 2;          // column 0..63 (and +64)
  const int kq = tid & 3;            // 8-elem chunk within 32-k
  const int bA = colbase_of(c0 + clA) + kq * 8;
  const int bB = colbase_of(c0 + 64 + clA) + kq * 8;

  const int lane = tid & 63;
  const int wave = tid >> 6;
  const int wr = wave >> 1, wc = wave & 1;
  const int arow = wr * 64 + (lane & 15);
  const int bcol = wc * 64 + (lane & 15);
  const int kbyte = (lane >> 4) * 16;

  f32x4 acc[4][4];
#pragma unroll
  for (int i = 0; i < 4; ++i)
#pragma unroll
    for (int j = 0; j < 4; ++j) acc[i][j] = (f32x4){0.f, 0.f, 0.f, 0.f};

  uint4 va = *(const uint4*)(xs + bA + BOFF(0));
  uint4 vb = *(const uint4*)(xs + bB + BOFF(0));

  for (int kt = 0; kt < NKT; ++kt) {
    __syncthreads();
    const char* Ag = (const char*)At + (size_t)(kt * 512 + o0) * 64;
    __builtin_amdgcn_global_load_lds((glb_u32*)(Ag + tid * 16),
                                     (lds_u32*)((char*)Al + tid * 16), 16, 0, 0);
    __builtin_amdgcn_global_load_lds((glb_u32*)(Ag + 4096 + tid * 16),
                                     (lds_u32*)((char*)Al + 4096 + tid * 16), 16, 0, 0);
    *(uint4*)((char*)Bl + clA * 64 + kq * 16) = va;
    *(uint4*)((char*)Bl + 4096 + clA * 64 + kq * 16) = vb;
    __syncthreads();

    bf16x8 af[4], bfr[4];
#pragma unroll
    for (int mt = 0; mt < 4; ++mt)
      af[mt] = *(const bf16x8*)((const char*)Al + (arow + mt * 16) * 64 + kbyte);
#pragma unroll
    for (int nt = 0; nt < 4; ++nt)
      bfr[nt] = *(const bf16x8*)((const char*)Bl + (bcol + nt * 16) * 64 + kbyte);

    if (kt + 1 < NKT) {           // prefetch next B chunk; drained at next barrier
      int ofn = BOFF(kt + 1);
      va = *(const uint4*)(xs + bA + ofn);
      vb = *(const uint4*)(xs + bB + ofn);
    }
#pragma unroll
    for (int mt = 0; mt < 4; ++mt)
#pragma unroll
      for (int nt = 0; nt < 4; ++nt)
        acc[mt][nt] = __builtin_amdgcn_mfma_f32_16x16x32_bf16(af[mt], bfr[nt], acc[mt][nt], 0, 0, 0);
  }

  // epilogue: *d[n,o] + bias[o], store bf16 NCHW [16][512][66][66]
  const int cb2 = c0 + wc * 64 + (lane & 15);
  const int rb = o0 + wr * 64 + ((lane >> 4) << 2);
#pragma unroll
  for (int nt = 0; nt < 4; ++nt) {
    int c = cb2 + nt * 16;
    if (c < NCOLS) {
      int n = (int)((unsigned)c / 4356u);
      int cadr = c + n * 2225916;   // == n*512*4356 + p*66 + q
#pragma unroll
      for (int mt = 0; mt < 4; ++mt) {
#pragma unroll
        for (int reg = 0; reg < 4; ++reg) {
          int o = rb + mt * 16 + reg;
          float v = acc[mt][nt][reg] * dnorm[n * 512 + o] + cbias[o];
          cvt[cadr + o * 4356] = __float2bfloat16(v);
        }
      }
    }
  }
}

// ---------------- fused filtered_lrelu: up2 (12-tap sep FIR) -> lrelu -> down2 ----------------
__global__ __launch_bounds__(256) void k_flrelu(
    const __hip_bfloat16* __restrict__ cvt, const float* __restrict__ fup,
    const float* __restrict__ fdn, float* __restrict__ out) {
  const int tile = blockIdx.x;       // 0..3 -> 32x32 output tile
  const int ch = blockIdx.y;
  const int n = blockIdx.z;
  const int oy0 = (tile >> 1) * 32;
  const int ox0 = (tile & 1) * 32;
  const int tid = threadIdx.x;

  __shared__ float yb_s[43][44];   // coarse input halo
  __shared__ float v_s[74][44];    // vertical up-FIR
  __shared__ float g_s[74][76];    // fine grid after lrelu
  __shared__ float dh_s[74][32];   // horizontal down
  __shared__ float fu[12], fd[12];

  if (tid < 12) fu[tid] = fup[tid];
  else if (tid < 24) fd[tid - 12] = fdn[tid - 12];

  const int i0 = oy0 - 4, j0 = ox0 - 4;
  const __hip_bfloat16* src = cvt + (n * 512 + ch) * 4356;

  // step 1: load 43x43 (zero outside [0,66)^2)
  for (int e = tid; e < 43 * 43; e += 256) {
    int il = e / 43, jl = e - il * 43;
    int i = i0 + il, j = j0 + jl;
    float v = 0.f;
    if (i >= 0 && i < 66 && j >= 0 && j < 66) v = __bfloat162float(src[i * 66 + j]);
    yb_s[il][jl] = v;
  }
  __syncthreads();

  // step 2: vertical up-FIR (polyphase, 6 taps): v[fyl][jl]
  for (int e = tid; e < 74 * 43; e += 256) {
    int fyl = e / 43, jl = e - fyl * 43;
    int sy = (fyl + 1) & 1;
    int il = (fyl + sy - 1) >> 1;
    float acc = 0.f;
#pragma unroll
    for (int t = 0; t < 6; ++t) acc += fu[sy + 2 * t] * yb_s[il + t][jl];
    v_s[fyl][jl] = acc;
  }
  __syncthreads();

  // step 3: horizontal up-FIR + gain*4 + lrelu*sqrt2 + clamp
  for (int e = tid; e < 74 * 74; e += 256) {
    int fyl = e / 74, fxl = e - fyl * 74;
    int sx = (fxl + 1) & 1;
    int jl = (fxl + sx - 1) >> 1;
    float acc = 0.f;
#pragma unroll
    for (int t = 0; t < 6; ++t) acc += fu[sx + 2 * t] * v_s[fyl][jl + t];
    acc *= 4.f;
    acc = (acc >= 0.f ? acc : 0.2f * acc) * 1.4142135623730951f;
    acc = fminf(fmaxf(acc, -256.f), 256.f);
    g_s[fyl][fxl] = acc;
  }
  __syncthreads();

  // step 4: horizontal down (stride 2, 12 taps)
  for (int e = tid; e < 74 * 32; e += 256) {
    int fyl = e >> 5, oxl = e & 31;
    float acc = 0.f;
#pragma unroll
    for (int t = 0; t < 12; ++t) acc += fd[t] * g_s[fyl][2 * oxl + t];
    dh_s[fyl][oxl] = acc;
  }
  __syncthreads();

  // step 5: vertical down + store
  float* dst = out + ((n * 512 + ch) * 64 + oy0) * 64 + ox0;
  for (int e = tid; e < 32 * 32; e += 256) {
    int oyl = e >> 5, oxl = e & 31;
    float acc = 0.f;
#pragma unroll
    for (int t = 0; t < 12; ++t) acc += fd[t] * dh_s[2 * oyl + t][oxl];
    dst[oyl * 64 + oxl] = acc;
  }
}

extern "C" void kernel_launch(void* const* d_in, const int* in_sizes, int n_in,
                              void* d_out, int out_size, void* d_ws, size_t ws_size,
                              hipStream_t stream) {
  const float* x = (const float*)d_in[0];
  const float* w = (const float*)d_in[1];
  const float* aw = (const float*)d_in[2];
  const float* ab = (const float*)d_in[3];
  const float* cw = (const float*)d_in[4];
  const float* cb = (const float*)d_in[5];
  const float* fu = (const float*)d_in[6];
  const float* fd = (const float*)d_in[7];
  char* ws = (char*)d_ws;
  float* styles = (float*)(ws + WS_STYLES);
  float* snorm = (float*)(ws + WS_SNORM);
  float* dmat = (float*)(ws + WS_D);
  float* W2 = (float*)(ws + WS_W2);
  __hip_bfloat16* At = (__hip_bfloat16*)(ws + WS_AT);
  __hip_bfloat16* xs = (__hip_bfloat16*)(ws + WS_XS);
  __hip_bfloat16* cvt = (__hip_bfloat16*)(ws + WS_CONV);
  float* out = (float*)d_out;

  k_styles<<<32, 256, 0, stream>>>(w, aw, ab, styles);
  k_snorm<<<1, 256, 0, stream>>>(styles, snorm);
  k_wprep<<<512, 256, 0, stream>>>(cw, At, W2);
  k_dcalc<<<32, 256, 0, stream>>>(W2, styles, snorm, dmat);
  k_zero<<<4096, 256, 0, stream>>>((uint4*)xs, 75759616L / 16L);
  k_scale_tr<<<dim3(8, 64, 16), 256, 0, stream>>>(x, styles, snorm, xs);
  k_gemm<<<dim3(4, 545), 256, 0, stream>>>(At, xs, dmat, cb, cvt);
  k_flrelu<<<dim3(4, 512, 16), 256, 0, stream>>>(cvt, fu, fd, out);
}

// Round 2
// 1120.017 us; speedup vs baseline: 1.0006x; 1.0006x over previous
//
#include <hip/hip_runtime.h>
#include <hip/hip_bf16.h>

typedef __attribute__((ext_vector_type(8))) short bf16x8;
typedef __attribute__((ext_vector_type(4))) float f32x4;
typedef unsigned int u32;
typedef const __attribute__((address_space(1))) u32 glb_u32;
typedef __attribute__((address_space(3))) u32 lds_u32;

#define NB 16
#define CI 512
#define CO 512
#define RESO 64
#define PC 66              // conv output spatial (64 + 2*2 - 3 + 1)
#define PADD 68            // padded input spatial
#define NCOLS (NB*PC*PC)   // 69696
#define NKT 144            // 4608 / 32

// workspace layout (bytes)
#define WS_STYLES 0ul              // 8192 f32
#define WS_SNORM  32768ul          // 1 f32
#define WS_D      33024ul          // 8192 f32
#define WS_W2     65792ul          // 512*512 f32
#define WS_AT     1114368ul        // 144*512*32 bf16 = 4718592
#define WS_XS     5832960ul        // 16*68*68*512 bf16 = 75759616
#define WS_CONV   81592576ul       // 16*512*66*66 bf16 = 71368704

// ---------------- styles = w @ aw^T / sqrt(512) + bias ----------------
__global__ void k_styles(const float* __restrict__ w, const float* __restrict__ aw,
                         const float* __restrict__ ab, float* __restrict__ styles) {
  int idx = blockIdx.x * 256 + threadIdx.x;   // 8192 = 16*512
  int n = idx >> 9, i = idx & 511;
  const float* wr = w + n * 512;
  const float* ar = aw + i * 512;
  float s = 0.f;
  for (int j = 0; j < 512; ++j) s += wr[j] * ar[j];
  styles[idx] = s * 0.04419417382415922f + ab[i];
}

// ---------------- snorm = rsqrt(mean(styles^2)) ----------------
__global__ void k_snorm(const float* __restrict__ styles, float* __restrict__ snorm) {
  __shared__ float red[256];
  float s = 0.f;
  for (int e = threadIdx.x; e < 8192; e += 256) { float v = styles[e]; s += v * v; }
  red[threadIdx.x] = s;
  __syncthreads();
  for (int st = 128; st > 0; st >>= 1) {
    if (threadIdx.x < st) red[threadIdx.x] += red[threadIdx.x + st];
    __syncthreads();
  }
  if (threadIdx.x == 0) snorm[0] = rsqrtf(red[0] / 8192.f);
}

// ---------------- weight prep: normalize per-o, write tiled bf16 A + W2 ----------------
__global__ void k_wprep(const float* __restrict__ cw, __hip_bfloat16* __restrict__ At,
                        float* __restrict__ W2) {
  int o = blockIdx.x;
  const float* base = cw + o * 4608;
  __shared__ float red[256];
  __shared__ float wnorm_s;
  float s = 0.f;
  for (int e = threadIdx.x; e < 4608; e += 256) { float v = base[e]; s += v * v; }
  red[threadIdx.x] = s;
  __syncthreads();
  for (int st = 128; st > 0; st >>= 1) {
    if (threadIdx.x < st) red[threadIdx.x] += red[threadIdx.x + st];
    __syncthreads();
  }
  if (threadIdx.x == 0) wnorm_s = rsqrtf(red[0] / 4608.f);
  __syncthreads();
  float wn = wnorm_s;
  for (int i = threadIdx.x; i < 512; i += 256) {
    const float* e9 = cw + (o * 512 + i) * 9;
    float w2 = 0.f;
    int ic = i >> 5, ik = i & 31;
#pragma unroll
    for (int rs = 0; rs < 9; ++rs) {
      float wv = e9[rs] * wn;
      w2 += wv * wv;
      At[((rs * 16 + ic) * 512 + o) * 32 + ik] = __float2bfloat16(wv);
    }
    W2[o * 512 + i] = w2;
  }
}

// ---------------- d[n,o] = rsqrt(snorm^2 * sum_i W2[o,i]*styles[n,i]^2 + 1e-8) ----------------
__global__ void k_dcalc(const float* __restrict__ W2, const float* __restrict__ styles,
                        const float* __restrict__ snorm, float* __restrict__ d) {
  int idx = blockIdx.x * 256 + threadIdx.x;   // n*512 + o
  int n = idx >> 9, o = idx & 511;
  const float* w2r = W2 + o * 512;
  const float* sr = styles + n * 512;
  float sum = 0.f;
  for (int i = 0; i < 512; ++i) { float sv = sr[i]; sum += w2r[i] * sv * sv; }
  float sn = snorm[0];
  d[idx] = rsqrtf(sn * sn * sum + 1e-8f);
}

// ---------------- zero only the pad border of xs ----------------
// per n: rows {0,1,66,67} full (4*68) + rows 2..65 cols {0,1,66,67} (64*4) = 528 cells
// each cell = 512 bf16 = 64 uint4 chunks
__global__ void k_zero_border(uint4* __restrict__ p) {
  int e = blockIdx.x * 256 + threadIdx.x;     // 16*528*64 = 540672
  if (e >= 16 * 528 * 64) return;
  int chunk = e & 63;
  int rest = e >> 6;
  int n = rest / 528;
  int pos = rest - n * 528;
  int row, col;
  if (pos < 272) {
    int r = pos / 68;
    row = (r < 2) ? r : r + 64;
    col = pos - r * 68;
  } else {
    int q = pos - 272;
    row = 2 + (q >> 2);
    int cs = q & 3;
    col = (cs < 2) ? cs : cs + 64;
  }
  uint4 z = {0u, 0u, 0u, 0u};
  p[(n * 4624 + row * 68 + col) * 64 + chunk] = z;
}

// ---------------- scale by s[n,i], transpose NCHW -> N,H+4,W+4,C (bf16) ----------------
__global__ void k_scale_tr(const float* __restrict__ x, const float* __restrict__ styles,
                           const float* __restrict__ snorm, __hip_bfloat16* __restrict__ xs) {
  const int i0 = blockIdx.x * 64;
  const int p = blockIdx.y;
  const int n = blockIdx.z;
  __shared__ float tile[64][65];
  const float sn = snorm[0];
  const int lo = threadIdx.x & 63;
  const int hi = threadIdx.x >> 6;
#pragma unroll 4
  for (int rep = 0; rep < 16; ++rep) {
    int ii = hi + rep * 4;
    float sc = styles[n * 512 + i0 + ii] * sn;
    tile[ii][lo] = x[((n * 512 + i0 + ii) * 64 + p) * 64 + lo] * sc;
  }
  __syncthreads();
  const int obase = (n * 4624 + (p + 2) * 68 + 2) * 512 + i0;
#pragma unroll 4
  for (int rep = 0; rep < 16; ++rep) {
    int q = hi + rep * 4;
    xs[obase + q * 512 + lo] = __float2bfloat16(tile[lo][q]);
  }
}

// ---------------- implicit GEMM conv ----------------
__device__ __forceinline__ int colbase_of(int c) {
  c = c < (NCOLS - 1) ? c : (NCOLS - 1);
  int n = (int)((unsigned)c / 4356u);
  int rem = c - n * 4356;
  int p = (int)((unsigned)rem / 66u);
  int q = rem - p * 66;
  return (n * 4624 + p * 68 + q) * 512;
}

#define BOFF(kt) (((((kt) >> 4) / 3) * 68 + (((kt) >> 4) % 3)) * 512 + ((kt) & 15) * 32)

__global__ __launch_bounds__(256) void k_gemm(
    const __hip_bfloat16* __restrict__ At, const __hip_bfloat16* __restrict__ xs,
    const float* __restrict__ dnorm, const float* __restrict__ cbias,
    __hip_bfloat16* __restrict__ cvt) {
  __shared__ __align__(16) __hip_bfloat16 Al[128 * 32];
  __shared__ __align__(16) __hip_bfloat16 Bl[128 * 32];
  const int tid = threadIdx.x;
  const int o0 = blockIdx.x * 128;   // 4 o-tiles
  const int c0 = blockIdx.y * 128;   // 545 col-tiles

  const int clA = tid >> 2;          // column 0..63 (and +64)
  const int kq = tid & 3;            // 8-elem chunk within 32-k
  // byte offsets into xs for this thread's 16B B chunk (column clA / clA+64)
  const size_t bA = (size_t)(colbase_of(c0 + clA) + kq * 8) * 2;
  const size_t bB = (size_t)(colbase_of(c0 + 64 + clA) + kq * 8) * 2;
  const char* xsc = (const char*)xs;

  const int lane = tid & 63;
  const int wave = tid >> 6;
  const int wr = wave >> 1, wc = wave & 1;
  const int arow = wr * 64 + (lane & 15);
  const int bcol = wc * 64 + (lane & 15);
  const int kbyte = (lane >> 4) * 16;

  f32x4 acc[4][4];
#pragma unroll
  for (int i = 0; i < 4; ++i)
#pragma unroll
    for (int j = 0; j < 4; ++j) acc[i][j] = (f32x4){0.f, 0.f, 0.f, 0.f};

  for (int kt = 0; kt < NKT; ++kt) {
    __syncthreads();
    const char* Ag = (const char*)At + (size_t)(kt * 512 + o0) * 64;
    __builtin_amdgcn_global_load_lds((glb_u32*)(Ag + tid * 16),
                                     (lds_u32*)((char*)Al + tid * 16), 16, 0, 0);
    __builtin_amdgcn_global_load_lds((glb_u32*)(Ag + 4096 + tid * 16),
                                     (lds_u32*)((char*)Al + 4096 + tid * 16), 16, 0, 0);
    const size_t boff = (size_t)BOFF(kt) * 2;
    __builtin_amdgcn_global_load_lds((glb_u32*)(xsc + bA + boff),
                                     (lds_u32*)((char*)Bl + tid * 16), 16, 0, 0);
    __builtin_amdgcn_global_load_lds((glb_u32*)(xsc + bB + boff),
                                     (lds_u32*)((char*)Bl + 4096 + tid * 16), 16, 0, 0);
    __syncthreads();

    bf16x8 af[4], bfr[4];
#pragma unroll
    for (int mt = 0; mt < 4; ++mt)
      af[mt] = *(const bf16x8*)((const char*)Al + (arow + mt * 16) * 64 + kbyte);
#pragma unroll
    for (int nt = 0; nt < 4; ++nt)
      bfr[nt] = *(const bf16x8*)((const char*)Bl + (bcol + nt * 16) * 64 + kbyte);

#pragma unroll
    for (int mt = 0; mt < 4; ++mt)
#pragma unroll
      for (int nt = 0; nt < 4; ++nt)
        acc[mt][nt] = __builtin_amdgcn_mfma_f32_16x16x32_bf16(af[mt], bfr[nt], acc[mt][nt], 0, 0, 0);
  }

  // epilogue: *d[n,o] + bias[o], store bf16 NCHW [16][512][66][66]
  const int cb2 = c0 + wc * 64 + (lane & 15);
  const int rb = o0 + wr * 64 + ((lane >> 4) << 2);
#pragma unroll
  for (int nt = 0; nt < 4; ++nt) {
    int c = cb2 + nt * 16;
    if (c < NCOLS) {
      int n = (int)((unsigned)c / 4356u);
      int cadr = c + n * 2225916;   // == n*512*4356 + p*66 + q
#pragma unroll
      for (int mt = 0; mt < 4; ++mt) {
#pragma unroll
        for (int reg = 0; reg < 4; ++reg) {
          int o = rb + mt * 16 + reg;
          float v = acc[mt][nt][reg] * dnorm[n * 512 + o] + cbias[o];
          cvt[cadr + o * 4356] = __float2bfloat16(v);
        }
      }
    }
  }
}

// ---------------- fused filtered_lrelu: full channel per block, sliding-window FIRs ----------------
// coarse halo: i,j in [-4,70] -> cs[75][76]; fine grid 138x138 implicit.
// union buffer: cs (75*76=5700 floats) reused as dh[138][67] (9246 floats)
#define CSW 76
#define VSW 77
#define DHW 67
__global__ __launch_bounds__(256) void k_flrelu(
    const __hip_bfloat16* __restrict__ cvt, const float* __restrict__ fup,
    const float* __restrict__ fdn, float* __restrict__ out) {
  const int ch = blockIdx.x;
  const int n = blockIdx.y;
  const int tid = threadIdx.x;

  __shared__ float u_s[9246];        // cs [75][76] then dh [138][67]
  __shared__ float vs_s[138 * VSW];  // vertical-up fine rows x coarse cols

  const float fu0 = fup[0], fu1 = fup[1], fu2 = fup[2], fu3 = fup[3];
  const float fu4 = fup[4], fu5 = fup[5], fu6 = fup[6], fu7 = fup[7];
  const float fu8 = fup[8], fu9 = fup[9], fu10 = fup[10], fu11 = fup[11];
  const float fd0 = fdn[0], fd1 = fdn[1], fd2 = fdn[2], fd3 = fdn[3];
  const float fd4 = fdn[4], fd5 = fdn[5], fd6 = fdn[6], fd7 = fdn[7];
  const float fd8 = fdn[8], fd9 = fdn[9], fd10 = fdn[10], fd11 = fdn[11];

  const __hip_bfloat16* src = cvt + (size_t)(n * 512 + ch) * 4356;

  // stage A: load coarse 75x75 halo (zero outside [0,66)^2)
  for (int e = tid; e < 75 * 75; e += 256) {
    int il = (int)((unsigned)e / 75u);
    int jl = e - il * 75;
    int i = il - 4, j = jl - 4;
    float v = 0.f;
    if (i >= 0 && i < 66 && j >= 0 && j < 66) v = __bfloat162float(src[i * 66 + j]);
    u_s[il * CSW + jl] = v;
  }
  __syncthreads();

  // stage B: vertical up-FIR, column threads, sliding 6-window.
  // fy=2m:   vs = sum_t fu[1+2t]*cs[m+t]
  // fy=2m+1: vs = sum_t fu[0+2t]*cs[m+t]
  if (tid < 225) {
    int r = tid / 75;            // band 0..2 -> pairs m in [23r, 23r+22]
    int jl = tid - r * 75;
    const float* col = u_s + jl;
    int m0 = 23 * r;
    float c0 = col[(m0 + 0) * CSW], c1 = col[(m0 + 1) * CSW], c2 = col[(m0 + 2) * CSW];
    float c3 = col[(m0 + 3) * CSW], c4 = col[(m0 + 4) * CSW];
    for (int mm = 0; mm < 23; ++mm) {
      int m = m0 + mm;
      float c5 = col[(m + 5) * CSW];
      float ve = fu1 * c0 + fu3 * c1 + fu5 * c2 + fu7 * c3 + fu9 * c4 + fu11 * c5;
      float vo = fu0 * c0 + fu2 * c1 + fu4 * c2 + fu6 * c3 + fu8 * c4 + fu10 * c5;
      vs_s[(2 * m) * VSW + jl] = ve;
      vs_s[(2 * m + 1) * VSW + jl] = vo;
      c0 = c1; c1 = c2; c2 = c3; c3 = c4; c4 = c5;
    }
  }
  __syncthreads();

  // stage C: fused h-up + lrelu + h-down per fine row, transposed-FIR accumulators.
  // task tt: fy = tt%138, h = tt/138 (h selects output cols [32h,32h+32))
  for (int tt = tid; tt < 276; tt += 256) {
    int h = tt / 138;
    int fy = tt - h * 138;
    const float* vrow = vs_s + fy * VSW + 32 * h;
    float* dhrow = u_s + fy * DHW + 32 * h;
    float a0 = 0.f, a1 = 0.f, a2 = 0.f, a3 = 0.f, a4 = 0.f, a5 = 0.f;
    float w0 = vrow[0], w1 = vrow[1], w2 = vrow[2], w3 = vrow[3], w4 = vrow[4];
#pragma unroll
    for (int ql = 0; ql < 37; ++ql) {
      float w5 = vrow[ql + 5];
      float ge = fu1 * w0 + fu3 * w1 + fu5 * w2 + fu7 * w3 + fu9 * w4 + fu11 * w5;
      float go = fu0 * w0 + fu2 * w1 + fu4 * w2 + fu6 * w3 + fu8 * w4 + fu10 * w5;
      // gain*4, lrelu*sqrt2, clamp
      ge *= (ge >= 0.f) ? 5.656854249492381f : 1.1313708498984762f;
      go *= (go >= 0.f) ? 5.656854249492381f : 1.1313708498984762f;
      ge = fminf(fmaxf(ge, -256.f), 256.f);
      go = fminf(fmaxf(go, -256.f), 256.f);
      a0 += fd10 * ge + fd11 * go;
      a1 += fd8 * ge + fd9 * go;
      a2 += fd6 * ge + fd7 * go;
      a3 += fd4 * ge + fd5 * go;
      a4 += fd2 * ge + fd3 * go;
      a5 += fd0 * ge + fd1 * go;
      if (ql >= 5) dhrow[ql - 5] = a0;
      a0 = a1; a1 = a2; a2 = a3; a3 = a4; a4 = a5; a5 = 0.f;
      w0 = w1; w1 = w2; w2 = w3; w3 = w4; w4 = w5;
    }
  }
  __syncthreads();

  // stage E: vertical down, 12-register sliding window, 2 new reads per output row.
  {
    int ox = tid & 63;
    int r = tid >> 6;                // band: oy in [16r, 16r+16)
    const float* dcol = u_s + ox;
    int f0 = 32 * r;
    float wreg[12];
#pragma unroll
    for (int k = 0; k < 10; ++k) wreg[k] = dcol[(f0 + k) * DHW];
    float* dst = out + (((size_t)(n * 512 + ch) * 64 + 16 * r) * 64) + ox;
#pragma unroll
    for (int oyl = 0; oyl < 16; ++oyl) {
      wreg[10] = dcol[(f0 + 2 * oyl + 10) * DHW];
      wreg[11] = dcol[(f0 + 2 * oyl + 11) * DHW];
      float s = fd0 * wreg[0] + fd1 * wreg[1] + fd2 * wreg[2] + fd3 * wreg[3] +
                fd4 * wreg[4] + fd5 * wreg[5] + fd6 * wreg[6] + fd7 * wreg[7] +
                fd8 * wreg[8] + fd9 * wreg[9] + fd10 * wreg[10] + fd11 * wreg[11];
      dst[oyl * 64] = s;
#pragma unroll
      for (int k = 0; k < 10; ++k) wreg[k] = wreg[k + 2];
    }
  }
}

extern "C" void kernel_launch(void* const* d_in, const int* in_sizes, int n_in,
                              void* d_out, int out_size, void* d_ws, size_t ws_size,
                              hipStream_t stream) {
  const float* x = (const float*)d_in[0];
  const float* w = (const float*)d_in[1];
  const float* aw = (const float*)d_in[2];
  const float* ab = (const float*)d_in[3];
  const float* cw = (const float*)d_in[4];
  const float* cb = (const float*)d_in[5];
  const float* fu = (const float*)d_in[6];
  const float* fd = (const float*)d_in[7];
  char* ws = (char*)d_ws;
  float* styles = (float*)(ws + WS_STYLES);
  float* snorm = (float*)(ws + WS_SNORM);
  float* dmat = (float*)(ws + WS_D);
  float* W2 = (float*)(ws + WS_W2);
  __hip_bfloat16* At = (__hip_bfloat16*)(ws + WS_AT);
  __hip_bfloat16* xs = (__hip_bfloat16*)(ws + WS_XS);
  __hip_bfloat16* cvt = (__hip_bfloat16*)(ws + WS_CONV);
  float* out = (float*)d_out;

  k_styles<<<32, 256, 0, stream>>>(w, aw, ab, styles);
  k_snorm<<<1, 256, 0, stream>>>(styles, snorm);
  k_wprep<<<512, 256, 0, stream>>>(cw, At, W2);
  k_dcalc<<<32, 256, 0, stream>>>(W2, styles, snorm, dmat);
  k_zero_border<<<(16 * 528 * 64 + 255) / 256, 256, 0, stream>>>((uint4*)xs);
  k_scale_tr<<<dim3(8, 64, 16), 256, 0, stream>>>(x, styles, snorm, xs);
  k_gemm<<<dim3(4, 545), 256, 0, stream>>>(At, xs, dmat, cb, cvt);
  k_flrelu<<<dim3(512, 16), 256, 0, stream>>>(cvt, fu, fd, out);
}

// Round 3
// 1034.148 us; speedup vs baseline: 1.0837x; 1.0830x over previous
//
#include <hip/hip_runtime.h>
#include <hip/hip_bf16.h>

typedef __attribute__((ext_vector_type(8))) short bf16x8;
typedef __attribute__((ext_vector_type(4))) float f32x4;
typedef unsigned int u32;
typedef const __attribute__((address_space(1))) u32 glb_u32;
typedef __attribute__((address_space(3))) u32 lds_u32;

#define NB 16
#define CI 512
#define CO 512
#define PC 66              // conv output spatial (64 + 2*2 - 3 + 1)
#define PADD 68            // padded input spatial
#define NCOLS (NB*PC*PC)   // 69696
#define NKT 144            // 4608 / 32

// workspace layout (bytes)
#define WS_STYLES 0ul              // 8192 f32
#define WS_SNORM  32768ul          // 1 f32
#define WS_D      33024ul          // 8192 f32
#define WS_W2     65792ul          // 512*512 f32
#define WS_AT     1114368ul        // 144*512*32 bf16 = 4718592
#define WS_XS     5832960ul        // 16*68*68*512 bf16 = 75759616
#define WS_CONV   81592576ul       // 16*512*66*66 bf16 = 71368704

// ---------------- styles = w @ aw^T / sqrt(512) + bias ----------------
__global__ void k_styles(const float* __restrict__ w, const float* __restrict__ aw,
                         const float* __restrict__ ab, float* __restrict__ styles) {
  int idx = blockIdx.x * 256 + threadIdx.x;   // 8192 = 16*512
  int n = idx >> 9, i = idx & 511;
  const float* wr = w + n * 512;
  const float* ar = aw + i * 512;
  float s = 0.f;
  for (int j = 0; j < 512; ++j) s += wr[j] * ar[j];
  styles[idx] = s * 0.04419417382415922f + ab[i];
}

// ---------------- snorm = rsqrt(mean(styles^2)) ----------------
__global__ void k_snorm(const float* __restrict__ styles, float* __restrict__ snorm) {
  __shared__ float red[256];
  float s = 0.f;
  for (int e = threadIdx.x; e < 8192; e += 256) { float v = styles[e]; s += v * v; }
  red[threadIdx.x] = s;
  __syncthreads();
  for (int st = 128; st > 0; st >>= 1) {
    if (threadIdx.x < st) red[threadIdx.x] += red[threadIdx.x + st];
    __syncthreads();
  }
  if (threadIdx.x == 0) snorm[0] = rsqrtf(red[0] / 8192.f);
}

// ---------------- weight prep: normalize per-o, write tiled bf16 A + W2 ----------------
// kt = ic*9 + rs  (ic = i>>5, rs = ry*3+rx); At[kt][o][ik]
__global__ void k_wprep(const float* __restrict__ cw, __hip_bfloat16* __restrict__ At,
                        float* __restrict__ W2) {
  int o = blockIdx.x;
  const float* base = cw + o * 4608;
  __shared__ float red[256];
  __shared__ float wnorm_s;
  float s = 0.f;
  for (int e = threadIdx.x; e < 4608; e += 256) { float v = base[e]; s += v * v; }
  red[threadIdx.x] = s;
  __syncthreads();
  for (int st = 128; st > 0; st >>= 1) {
    if (threadIdx.x < st) red[threadIdx.x] += red[threadIdx.x + st];
    __syncthreads();
  }
  if (threadIdx.x == 0) wnorm_s = rsqrtf(red[0] / 4608.f);
  __syncthreads();
  float wn = wnorm_s;
  for (int i = threadIdx.x; i < 512; i += 256) {
    const float* e9 = cw + (o * 512 + i) * 9;
    float w2 = 0.f;
    int ic = i >> 5, ik = i & 31;
#pragma unroll
    for (int rs = 0; rs < 9; ++rs) {
      float wv = e9[rs] * wn;
      w2 += wv * wv;
      At[((ic * 9 + rs) * 512 + o) * 32 + ik] = __float2bfloat16(wv);
    }
    W2[o * 512 + i] = w2;
  }
}

// ---------------- d[n,o] = rsqrt(snorm^2 * sum_i W2[o,i]*styles[n,i]^2 + 1e-8) ----------------
__global__ void k_dcalc(const float* __restrict__ W2, const float* __restrict__ styles,
                        const float* __restrict__ snorm, float* __restrict__ d) {
  int idx = blockIdx.x * 256 + threadIdx.x;   // n*512 + o
  int n = idx >> 9, o = idx & 511;
  const float* w2r = W2 + o * 512;
  const float* sr = styles + n * 512;
  float sum = 0.f;
  for (int i = 0; i < 512; ++i) { float sv = sr[i]; sum += w2r[i] * sv * sv; }
  float sn = snorm[0];
  d[idx] = rsqrtf(sn * sn * sum + 1e-8f);
}

// ---------------- zero only the pad border of xs ----------------
__global__ void k_zero_border(uint4* __restrict__ p) {
  int e = blockIdx.x * 256 + threadIdx.x;     // 16*528*64 = 540672
  if (e >= 16 * 528 * 64) return;
  int chunk = e & 63;
  int rest = e >> 6;
  int n = rest / 528;
  int pos = rest - n * 528;
  int row, col;
  if (pos < 272) {
    int r = pos / 68;
    row = (r < 2) ? r : r + 64;
    col = pos - r * 68;
  } else {
    int q = pos - 272;
    row = 2 + (q >> 2);
    int cs = q & 3;
    col = (cs < 2) ? cs : cs + 64;
  }
  uint4 z = {0u, 0u, 0u, 0u};
  p[(n * 4624 + row * 68 + col) * 64 + chunk] = z;
}

// ---------------- scale by s[n,i], transpose NCHW -> N,H+4,W+4,C (bf16) ----------------
__global__ void k_scale_tr(const float* __restrict__ x, const float* __restrict__ styles,
                           const float* __restrict__ snorm, __hip_bfloat16* __restrict__ xs) {
  const int i0 = blockIdx.x * 64;
  const int p = blockIdx.y;
  const int n = blockIdx.z;
  __shared__ float tile[64][65];
  const float sn = snorm[0];
  const int lo = threadIdx.x & 63;
  const int hi = threadIdx.x >> 6;
#pragma unroll 4
  for (int rep = 0; rep < 16; ++rep) {
    int ii = hi + rep * 4;
    float sc = styles[n * 512 + i0 + ii] * sn;
    tile[ii][lo] = x[((n * 512 + i0 + ii) * 64 + p) * 64 + lo] * sc;
  }
  __syncthreads();
  const int obase = (n * 4624 + (p + 2) * 68 + 2) * 512 + i0;
#pragma unroll 4
  for (int rep = 0; rep < 16; ++rep) {
    int q = hi + rep * 4;
    xs[obase + q * 512 + lo] = __float2bfloat16(tile[lo][q]);
  }
}

// ---------------- implicit GEMM conv ----------------
__device__ __forceinline__ int colbase_of(int c) {
  c = c < (NCOLS - 1) ? c : (NCOLS - 1);
  int n = (int)((unsigned)c / 4356u);
  int rem = c - n * 4356;
  int p = (int)((unsigned)rem / 66u);
  int q = rem - p * 66;
  return (n * 4624 + p * 68 + q) * 512;
}

__global__ __launch_bounds__(256) void k_gemm(
    const __hip_bfloat16* __restrict__ At, const __hip_bfloat16* __restrict__ xs,
    const float* __restrict__ dnorm, const float* __restrict__ cbias,
    __hip_bfloat16* __restrict__ cvt) {
  __shared__ __align__(16) __hip_bfloat16 Al[128 * 32];
  __shared__ __align__(16) __hip_bfloat16 Bl[128 * 32];
  const int tid = threadIdx.x;

  // XCD swizzle: 32 consecutive bids = 8 col-tiles x 4 o-slices; same-col blocks
  // are 8 apart -> same XCD under round-robin dispatch -> B tile shared in L2.
  const int bid = blockIdx.x;
  const int g = bid >> 5, r = bid & 31;
  int colt, ot;
  if (g < 68) { colt = g * 8 + (r & 7); ot = r >> 3; }
  else        { colt = 544;             ot = r; }
  const int o0 = ot * 128;
  const int c0 = colt * 128;

  const int clA = tid >> 2;          // column 0..63 (and +64)
  const int kq = tid & 3;            // 8-elem chunk within 32-k
  const size_t bA = (size_t)colbase_of(c0 + clA) * 2 + kq * 16;
  const size_t bB = (size_t)colbase_of(c0 + 64 + clA) * 2 + kq * 16;
  const char* xsc = (const char*)xs;

  const int lane = tid & 63;
  const int wave = tid >> 6;
  const int wr = wave >> 1, wc = wave & 1;
  const int arow = wr * 64 + (lane & 15);
  const int bcol = wc * 64 + (lane & 15);
  const int kbyte = (lane >> 4) * 16;

  // byte offset of cell (ry,rx) in xs row-major cells of 1024B; +ic*64 for chunk
  const int OFFc[9] = {0, 1024, 2048, 69632, 70656, 71680, 139264, 140288, 141312};

  f32x4 acc[4][4];
#pragma unroll
  for (int i = 0; i < 4; ++i)
#pragma unroll
    for (int j = 0; j < 4; ++j) acc[i][j] = (f32x4){0.f, 0.f, 0.f, 0.f};

  uint4 va = *(const uint4*)(xsc + bA);
  uint4 vb = *(const uint4*)(xsc + bB);

  for (int ic = 0; ic < 16; ++ic) {
#pragma unroll
    for (int rs = 0; rs < 9; ++rs) {
      __syncthreads();
      const char* Ag = (const char*)At + (size_t)((ic * 9 + rs) * 512 + o0) * 64;
      __builtin_amdgcn_global_load_lds((glb_u32*)(Ag + tid * 16),
                                       (lds_u32*)((char*)Al + tid * 16), 16, 0, 0);
      __builtin_amdgcn_global_load_lds((glb_u32*)(Ag + 4096 + tid * 16),
                                       (lds_u32*)((char*)Al + 4096 + tid * 16), 16, 0, 0);
      *(uint4*)((char*)Bl + clA * 64 + kq * 16) = va;
      *(uint4*)((char*)Bl + 4096 + clA * 64 + kq * 16) = vb;
      __syncthreads();

      bf16x8 af[4], bfr[4];
#pragma unroll
      for (int mt = 0; mt < 4; ++mt)
        af[mt] = *(const bf16x8*)((const char*)Al + (arow + mt * 16) * 64 + kbyte);
#pragma unroll
      for (int nt = 0; nt < 4; ++nt)
        bfr[nt] = *(const bf16x8*)((const char*)Bl + (bcol + nt * 16) * 64 + kbyte);

      // prefetch next (ic,rs) B chunk; consumed after next barrier
      if (!(ic == 15 && rs == 8)) {
        int nrs = (rs == 8) ? 0 : rs + 1;
        int nic = (rs == 8) ? ic + 1 : ic;
        size_t boff = (size_t)OFFc[nrs] + (size_t)nic * 64;
        va = *(const uint4*)(xsc + bA + boff);
        vb = *(const uint4*)(xsc + bB + boff);
      }
#pragma unroll
      for (int mt = 0; mt < 4; ++mt)
#pragma unroll
        for (int nt = 0; nt < 4; ++nt)
          acc[mt][nt] = __builtin_amdgcn_mfma_f32_16x16x32_bf16(af[mt], bfr[nt], acc[mt][nt], 0, 0, 0);
    }
  }

  // epilogue: *d[n,o] + bias[o], store bf16 NCHW [16][512][66][66]
  const int cb2 = c0 + wc * 64 + (lane & 15);
  const int rb = o0 + wr * 64 + ((lane >> 4) << 2);
#pragma unroll
  for (int nt = 0; nt < 4; ++nt) {
    int c = cb2 + nt * 16;
    if (c < NCOLS) {
      int n = (int)((unsigned)c / 4356u);
      int cadr = c + n * 2225916;   // == n*512*4356 + p*66 + q
#pragma unroll
      for (int mt = 0; mt < 4; ++mt) {
#pragma unroll
        for (int reg = 0; reg < 4; ++reg) {
          int o = rb + mt * 16 + reg;
          float v = acc[mt][nt][reg] * dnorm[n * 512 + o] + cbias[o];
          cvt[cadr + o * 4356] = __float2bfloat16(v);
        }
      }
    }
  }
}

// ---------------- fused filtered_lrelu: full channel per block, sliding-window FIRs ----------------
#define CSW 76
#define VSW 77
#define DHW 67
__global__ __launch_bounds__(256) void k_flrelu(
    const __hip_bfloat16* __restrict__ cvt, const float* __restrict__ fup,
    const float* __restrict__ fdn, float* __restrict__ out) {
  const int ch = blockIdx.x;
  const int n = blockIdx.y;
  const int tid = threadIdx.x;

  __shared__ float u_s[9246];        // cs [75][76] then dh [138][67]
  __shared__ float vs_s[138 * VSW];  // vertical-up fine rows x coarse cols

  const float fu0 = fup[0], fu1 = fup[1], fu2 = fup[2], fu3 = fup[3];
  const float fu4 = fup[4], fu5 = fup[5], fu6 = fup[6], fu7 = fup[7];
  const float fu8 = fup[8], fu9 = fup[9], fu10 = fup[10], fu11 = fup[11];
  const float fd0 = fdn[0], fd1 = fdn[1], fd2 = fdn[2], fd3 = fdn[3];
  const float fd4 = fdn[4], fd5 = fdn[5], fd6 = fdn[6], fd7 = fdn[7];
  const float fd8 = fdn[8], fd9 = fdn[9], fd10 = fdn[10], fd11 = fdn[11];

  const __hip_bfloat16* src = cvt + (size_t)(n * 512 + ch) * 4356;

  // stage A: load coarse 75x75 halo (zero outside [0,66)^2)
  for (int e = tid; e < 75 * 75; e += 256) {
    int il = (int)((unsigned)e / 75u);
    int jl = e - il * 75;
    int i = il - 4, j = jl - 4;
    float v = 0.f;
    if (i >= 0 && i < 66 && j >= 0 && j < 66) v = __bfloat162float(src[i * 66 + j]);
    u_s[il * CSW + jl] = v;
  }
  __syncthreads();

  // stage B: vertical up-FIR, column threads, sliding 6-window
  if (tid < 225) {
    int r = tid / 75;            // band 0..2 -> pairs m in [23r, 23r+22]
    int jl = tid - r * 75;
    const float* col = u_s + jl;
    int m0 = 23 * r;
    float c0 = col[(m0 + 0) * CSW], c1 = col[(m0 + 1) * CSW], c2 = col[(m0 + 2) * CSW];
    float c3 = col[(m0 + 3) * CSW], c4 = col[(m0 + 4) * CSW];
    for (int mm = 0; mm < 23; ++mm) {
      int m = m0 + mm;
      float c5 = col[(m + 5) * CSW];
      float ve = fu1 * c0 + fu3 * c1 + fu5 * c2 + fu7 * c3 + fu9 * c4 + fu11 * c5;
      float vo = fu0 * c0 + fu2 * c1 + fu4 * c2 + fu6 * c3 + fu8 * c4 + fu10 * c5;
      vs_s[(2 * m) * VSW + jl] = ve;
      vs_s[(2 * m + 1) * VSW + jl] = vo;
      c0 = c1; c1 = c2; c2 = c3; c3 = c4; c4 = c5;
    }
  }
  __syncthreads();

  // stage C: fused h-up + lrelu + h-down per fine row, transposed-FIR accumulators
  for (int tt = tid; tt < 276; tt += 256) {
    int h = tt / 138;
    int fy = tt - h * 138;
    const float* vrow = vs_s + fy * VSW + 32 * h;
    float* dhrow = u_s + fy * DHW + 32 * h;
    float a0 = 0.f, a1 = 0.f, a2 = 0.f, a3 = 0.f, a4 = 0.f, a5 = 0.f;
    float w0 = vrow[0], w1 = vrow[1], w2 = vrow[2], w3 = vrow[3], w4 = vrow[4];
#pragma unroll
    for (int ql = 0; ql < 37; ++ql) {
      float w5 = vrow[ql + 5];
      float ge = fu1 * w0 + fu3 * w1 + fu5 * w2 + fu7 * w3 + fu9 * w4 + fu11 * w5;
      float go = fu0 * w0 + fu2 * w1 + fu4 * w2 + fu6 * w3 + fu8 * w4 + fu10 * w5;
      ge *= (ge >= 0.f) ? 5.656854249492381f : 1.1313708498984762f;
      go *= (go >= 0.f) ? 5.656854249492381f : 1.1313708498984762f;
      ge = fminf(fmaxf(ge, -256.f), 256.f);
      go = fminf(fmaxf(go, -256.f), 256.f);
      a0 += fd10 * ge + fd11 * go;
      a1 += fd8 * ge + fd9 * go;
      a2 += fd6 * ge + fd7 * go;
      a3 += fd4 * ge + fd5 * go;
      a4 += fd2 * ge + fd3 * go;
      a5 += fd0 * ge + fd1 * go;
      if (ql >= 5) dhrow[ql - 5] = a0;
      a0 = a1; a1 = a2; a2 = a3; a3 = a4; a4 = a5; a5 = 0.f;
      w0 = w1; w1 = w2; w2 = w3; w3 = w4; w4 = w5;
    }
  }
  __syncthreads();

  // stage E: vertical down, 12-register sliding window
  {
    int ox = tid & 63;
    int r = tid >> 6;                // band: oy in [16r, 16r+16)
    const float* dcol = u_s + ox;
    int f0 = 32 * r;
    float wreg[12];
#pragma unroll
    for (int k = 0; k < 10; ++k) wreg[k] = dcol[(f0 + k) * DHW];
    float* dst = out + (((size_t)(n * 512 + ch) * 64 + 16 * r) * 64) + ox;
#pragma unroll
    for (int oyl = 0; oyl < 16; ++oyl) {
      wreg[10] = dcol[(f0 + 2 * oyl + 10) * DHW];
      wreg[11] = dcol[(f0 + 2 * oyl + 11) * DHW];
      float s = fd0 * wreg[0] + fd1 * wreg[1] + fd2 * wreg[2] + fd3 * wreg[3] +
                fd4 * wreg[4] + fd5 * wreg[5] + fd6 * wreg[6] + fd7 * wreg[7] +
                fd8 * wreg[8] + fd9 * wreg[9] + fd10 * wreg[10] + fd11 * wreg[11];
      dst[oyl * 64] = s;
#pragma unroll
      for (int k = 0; k < 10; ++k) wreg[k] = wreg[k + 2];
    }
  }
}

extern "C" void kernel_launch(void* const* d_in, const int* in_sizes, int n_in,
                              void* d_out, int out_size, void* d_ws, size_t ws_size,
                              hipStream_t stream) {
  const float* x = (const float*)d_in[0];
  const float* w = (const float*)d_in[1];
  const float* aw = (const float*)d_in[2];
  const float* ab = (const float*)d_in[3];
  const float* cw = (const float*)d_in[4];
  const float* cb = (const float*)d_in[5];
  const float* fu = (const float*)d_in[6];
  const float* fd = (const float*)d_in[7];
  char* ws = (char*)d_ws;
  float* styles = (float*)(ws + WS_STYLES);
  float* snorm = (float*)(ws + WS_SNORM);
  float* dmat = (float*)(ws + WS_D);
  float* W2 = (float*)(ws + WS_W2);
  __hip_bfloat16* At = (__hip_bfloat16*)(ws + WS_AT);
  __hip_bfloat16* xs = (__hip_bfloat16*)(ws + WS_XS);
  __hip_bfloat16* cvt = (__hip_bfloat16*)(ws + WS_CONV);
  float* out = (float*)d_out;

  k_styles<<<32, 256, 0, stream>>>(w, aw, ab, styles);
  k_snorm<<<1, 256, 0, stream>>>(styles, snorm);
  k_wprep<<<512, 256, 0, stream>>>(cw, At, W2);
  k_dcalc<<<32, 256, 0, stream>>>(W2, styles, snorm, dmat);
  k_zero_border<<<(16 * 528 * 64 + 255) / 256, 256, 0, stream>>>((uint4*)xs);
  k_scale_tr<<<dim3(8, 64, 16), 256, 0, stream>>>(x, styles, snorm, xs);
  k_gemm<<<2180, 256, 0, stream>>>(At, xs, dmat, cb, cvt);
  k_flrelu<<<dim3(512, 16), 256, 0, stream>>>(cvt, fu, fd, out);
}